// Round 1
// baseline (149.460 us; speedup 1.0000x reference)
//
#include <hip/hip_runtime.h>
#include <stdint.h>

// Problem: logits = (mem^T @ x)/16 ; attn = softmax_M(logits) ; out = mem @ attn
// B=8, K=256, M=1024, N=4096. Fully fused: logits written once, attn never in HBM.

typedef __attribute__((ext_vector_type(8))) __bf16 bf16x8;
typedef __attribute__((ext_vector_type(4))) float f32x4;

#define BQ 8
#define KD 256
#define MD 1024
#define ND 4096
#define NT 32

__device__ __forceinline__ unsigned short bf16_rne(float f) {
    union { float f; uint32_t u; } c; c.f = f;
    uint32_t u = c.u;
    uint32_t r = (u + 0x7FFFu + ((u >> 16) & 1u)) >> 16;
    return (unsigned short)r;
}

// mem (f32 256x1024) -> mT bf16 [1024][256] (GEMM1 A), mR bf16 [256][1024] (GEMM2 A)
__global__ void prep_mem(const float* __restrict__ mem,
                         unsigned short* __restrict__ mT,
                         unsigned short* __restrict__ mR) {
    const int k = blockIdx.x;   // 0..255
    const int t = threadIdx.x;  // 0..255
    float4 v = reinterpret_cast<const float4*>(mem + (size_t)k * MD)[t];
    unsigned short h0 = bf16_rne(v.x), h1 = bf16_rne(v.y),
                   h2 = bf16_rne(v.z), h3 = bf16_rne(v.w);
    reinterpret_cast<uint2*>(mR + (size_t)k * MD)[t] =
        make_uint2((uint32_t)h0 | ((uint32_t)h1 << 16),
                   (uint32_t)h2 | ((uint32_t)h3 << 16));
    const int mm = t * 4;
    mT[(size_t)(mm + 0) * KD + k] = h0;
    mT[(size_t)(mm + 1) * KD + k] = h1;
    mT[(size_t)(mm + 2) * KD + k] = h2;
    mT[(size_t)(mm + 3) * KD + k] = h3;
}

// One workgroup = (batch b, 32-column strip). 16 waves.
// LDS (64 KiB, aliased over time):
//   phase 1: x tile   [n=32][k=256] bf16, 16B-chunk XOR swizzle (chunk ^= n&7)
//   phase 2: red scratch at +32768 (max) / +34816 (sum)
//   phase 3: attn tile [n=32][m=1024] bf16, 16B-chunk XOR swizzle (chunk ^= n&7)
__global__ __launch_bounds__(1024) void fused_attn_mem(
    const float* __restrict__ x,
    const unsigned short* __restrict__ mT,
    const unsigned short* __restrict__ mR,
    float* __restrict__ out,
    float* __restrict__ logits)
{
    __shared__ __align__(16) char lds[65536];
    float* red_max = (float*)(lds + 32768);          // [16 waves][2 ct][16 cols]
    float* red_sum = (float*)(lds + 32768 + 2048);

    const int tid = threadIdx.x;
    const int w   = tid >> 6;     // wave 0..15
    const int l   = tid & 63;
    const int l15 = l & 15;
    const int l4  = l >> 4;       // 0..3

    const int bid = blockIdx.x;
    const int b   = bid >> 7;          // 8 batches
    const int n0  = (bid & 127) * NT;  // column strip

    // ---- stage x[b][0:256][n0:n0+32] -> LDS transposed+swizzled ----
    {
        const float* xb = x + (size_t)b * KD * ND + n0;
        const int n  = tid & 31;
        const int k0 = tid >> 5;  // 0..31
        #pragma unroll
        for (int i = 0; i < 8; ++i) {
            const int k = k0 + i * 32;
            const float v = xb[(size_t)k * ND + n];
            const unsigned short h = bf16_rne(v);
            const int off = n * 512 + (((k >> 3) ^ (n & 7)) << 4) + (k & 7) * 2;
            *(unsigned short*)(lds + off) = h;
        }
    }
    __syncthreads();

    // ---- GEMM1: S[m][n] = sum_k mT[m][k] * x[k][n], wave owns rows [w*64, w*64+64) ----
    f32x4 acc[4][2];
    #pragma unroll
    for (int rt = 0; rt < 4; ++rt)
        #pragma unroll
        for (int ct = 0; ct < 2; ++ct)
            acc[rt][ct] = (f32x4){0.f, 0.f, 0.f, 0.f};

    #pragma unroll
    for (int ks = 0; ks < 8; ++ks) {
        const int kk = ks * 32 + l4 * 8;   // k base for this lane's fragment
        bf16x8 bfr[2];
        #pragma unroll
        for (int ct = 0; ct < 2; ++ct) {
            const int n = ct * 16 + l15;
            const int off = n * 512 + (((kk >> 3) ^ (n & 7)) << 4);
            bfr[ct] = *(const bf16x8*)(lds + off);
        }
        #pragma unroll
        for (int rt = 0; rt < 4; ++rt) {
            const int row = w * 64 + rt * 16 + l15;
            const bf16x8 afr = *(const bf16x8*)(mT + (size_t)row * KD + kk);
            acc[rt][0] = __builtin_amdgcn_mfma_f32_16x16x32_bf16(afr, bfr[0], acc[rt][0], 0, 0, 0);
            acc[rt][1] = __builtin_amdgcn_mfma_f32_16x16x32_bf16(afr, bfr[1], acc[rt][1], 0, 0, 0);
        }
    }

    // ---- scale 1/16, write logits, per-column max ----
    float lmax[2] = {-1e30f, -1e30f};
    float* lg = logits + (size_t)b * MD * ND + n0;
    #pragma unroll
    for (int rt = 0; rt < 4; ++rt) {
        #pragma unroll
        for (int ct = 0; ct < 2; ++ct) {
            f32x4 v = acc[rt][ct] * 0.0625f;
            acc[rt][ct] = v;
            const int m0 = w * 64 + rt * 16 + l4 * 4;
            const int n  = ct * 16 + l15;
            float* d = lg + (size_t)m0 * ND + n;
            d[0]              = v[0];
            d[(size_t)ND]     = v[1];
            d[(size_t)2 * ND] = v[2];
            d[(size_t)3 * ND] = v[3];
            lmax[ct] = fmaxf(lmax[ct], fmaxf(fmaxf(v[0], v[1]), fmaxf(v[2], v[3])));
        }
    }
    #pragma unroll
    for (int ct = 0; ct < 2; ++ct) {
        float m = lmax[ct];
        m = fmaxf(m, __shfl_xor(m, 16, 64));
        m = fmaxf(m, __shfl_xor(m, 32, 64));
        lmax[ct] = m;
    }
    if (l < 16) {
        red_max[(w * 2 + 0) * 16 + l] = lmax[0];
        red_max[(w * 2 + 1) * 16 + l] = lmax[1];
    }
    __syncthreads();

    float cmax[2];
    #pragma unroll
    for (int ct = 0; ct < 2; ++ct) {
        float m = -1e30f;
        for (int ww = 0; ww < 16; ++ww)
            m = fmaxf(m, red_max[(ww * 2 + ct) * 16 + l15]);
        cmax[ct] = m;
    }

    // ---- p = exp(logit - colmax), per-column sum ----
    float lsum[2] = {0.f, 0.f};
    #pragma unroll
    for (int rt = 0; rt < 4; ++rt) {
        #pragma unroll
        for (int ct = 0; ct < 2; ++ct) {
            f32x4 v = acc[rt][ct];
            v[0] = __expf(v[0] - cmax[ct]);
            v[1] = __expf(v[1] - cmax[ct]);
            v[2] = __expf(v[2] - cmax[ct]);
            v[3] = __expf(v[3] - cmax[ct]);
            lsum[ct] += (v[0] + v[1]) + (v[2] + v[3]);
            acc[rt][ct] = v;
        }
    }
    #pragma unroll
    for (int ct = 0; ct < 2; ++ct) {
        float s = lsum[ct];
        s += __shfl_xor(s, 16, 64);
        s += __shfl_xor(s, 32, 64);
        lsum[ct] = s;
    }
    if (l < 16) {
        red_sum[(w * 2 + 0) * 16 + l] = lsum[0];
        red_sum[(w * 2 + 1) * 16 + l] = lsum[1];
    }
    __syncthreads();

    float rs[2];
    #pragma unroll
    for (int ct = 0; ct < 2; ++ct) {
        float s = 0.f;
        for (int ww = 0; ww < 16; ++ww)
            s += red_sum[(ww * 2 + ct) * 16 + l15];
        rs[ct] = 1.0f / s;
    }
    __syncthreads();   // all red reads done; attn writes may now overwrite LDS

    // ---- attn (bf16) into LDS, [n][m] with 16B-chunk XOR swizzle ----
    #pragma unroll
    for (int rt = 0; rt < 4; ++rt) {
        #pragma unroll
        for (int ct = 0; ct < 2; ++ct) {
            f32x4 v = acc[rt][ct];
            unsigned short h0 = bf16_rne(v[0] * rs[ct]);
            unsigned short h1 = bf16_rne(v[1] * rs[ct]);
            unsigned short h2 = bf16_rne(v[2] * rs[ct]);
            unsigned short h3 = bf16_rne(v[3] * rs[ct]);
            const int m0 = w * 64 + rt * 16 + l4 * 4;
            const int n  = ct * 16 + l15;
            const int off = n * 2048 + (((m0 >> 3) ^ (n & 7)) << 4) + (m0 & 7) * 2;
            *(uint2*)(lds + off) = make_uint2((uint32_t)h0 | ((uint32_t)h1 << 16),
                                              (uint32_t)h2 | ((uint32_t)h3 << 16));
        }
    }
    __syncthreads();

    // ---- GEMM2: out[r][n] = sum_m mR[r][m] * attn[m][n], wave owns rows [w*16, w*16+16) ----
    f32x4 acc2[2];
    acc2[0] = (f32x4){0.f, 0.f, 0.f, 0.f};
    acc2[1] = (f32x4){0.f, 0.f, 0.f, 0.f};
    const unsigned short* arow = mR + (size_t)(w * 16 + l15) * MD;
    #pragma unroll 4
    for (int ks = 0; ks < 32; ++ks) {
        const int mk = ks * 32 + l4 * 8;
        const bf16x8 a2 = *(const bf16x8*)(arow + mk);
        #pragma unroll
        for (int ct = 0; ct < 2; ++ct) {
            const int n = ct * 16 + l15;
            const int off = n * 2048 + (((mk >> 3) ^ (n & 7)) << 4);
            const bf16x8 b2 = *(const bf16x8*)(lds + off);
            acc2[ct] = __builtin_amdgcn_mfma_f32_16x16x32_bf16(a2, b2, acc2[ct], 0, 0, 0);
        }
    }

    float* ob = out + (size_t)b * KD * ND + n0;
    #pragma unroll
    for (int ct = 0; ct < 2; ++ct) {
        const int n  = ct * 16 + l15;
        const int r0 = w * 16 + l4 * 4;
        ob[(size_t)(r0 + 0) * ND + n] = acc2[ct][0];
        ob[(size_t)(r0 + 1) * ND + n] = acc2[ct][1];
        ob[(size_t)(r0 + 2) * ND + n] = acc2[ct][2];
        ob[(size_t)(r0 + 3) * ND + n] = acc2[ct][3];
    }
}

extern "C" void kernel_launch(void* const* d_in, const int* in_sizes, int n_in,
                              void* d_out, int out_size, void* d_ws, size_t ws_size,
                              hipStream_t stream) {
    (void)in_sizes; (void)n_in; (void)out_size; (void)ws_size;
    const float* x   = (const float*)d_in[0];
    // d_in[1] (mask) is a forward no-op
    const float* mem = (const float*)d_in[2];

    float* out    = (float*)d_out;
    float* logits = (float*)d_out + (size_t)BQ * KD * ND;

    unsigned short* mT = (unsigned short*)d_ws;        // [1024][256] bf16
    unsigned short* mR = mT + (size_t)MD * KD;         // [256][1024] bf16

    prep_mem<<<dim3(256), dim3(256), 0, stream>>>(mem, mT, mR);
    fused_attn_mem<<<dim3(BQ * (ND / NT)), dim3(1024), 0, stream>>>(x, mT, mR, out, logits);
}

// Round 2
// 138.704 us; speedup vs baseline: 1.0775x; 1.0775x over previous
//
#include <hip/hip_runtime.h>
#include <stdint.h>

// logits = (mem^T @ x)/16 ; attn = softmax_M(logits) ; out = mem @ attn
// B=8, K=256, M=1024, N=4096. Fully fused: logits written once, attn never in HBM.

typedef __attribute__((ext_vector_type(8))) __bf16 bf16x8;
typedef __attribute__((ext_vector_type(4))) float f32x4;

#define BQ 8
#define KD 256
#define MD 1024
#define ND 4096
#define NT 32

__device__ __forceinline__ unsigned short bf16_rne(float f) {
    union { float f; uint32_t u; } c; c.f = f;
    uint32_t u = c.u;
    uint32_t r = (u + 0x7FFFu + ((u >> 16) & 1u)) >> 16;
    return (unsigned short)r;
}

// mem (f32 256x1024) -> mT bf16 [1024][256] (GEMM1 A-frags), mR bf16 [256][1024] (GEMM2 A-frags)
__global__ void prep_mem(const float* __restrict__ mem,
                         unsigned short* __restrict__ mT,
                         unsigned short* __restrict__ mR) {
    const int k = blockIdx.x;   // 0..255
    const int t = threadIdx.x;  // 0..255
    float4 v = reinterpret_cast<const float4*>(mem + (size_t)k * MD)[t];
    unsigned short h0 = bf16_rne(v.x), h1 = bf16_rne(v.y),
                   h2 = bf16_rne(v.z), h3 = bf16_rne(v.w);
    reinterpret_cast<uint2*>(mR + (size_t)k * MD)[t] =
        make_uint2((uint32_t)h0 | ((uint32_t)h1 << 16),
                   (uint32_t)h2 | ((uint32_t)h3 << 16));
    const int mm = t * 4;
    mT[(size_t)(mm + 0) * KD + k] = h0;
    mT[(size_t)(mm + 1) * KD + k] = h1;
    mT[(size_t)(mm + 2) * KD + k] = h2;
    mT[(size_t)(mm + 3) * KD + k] = h3;
}

// One workgroup = (batch b, 32-column strip). 8 waves, 512 threads, 2 blocks/CU.
// LDS 64 KiB, aliased over time:
//   [0,16K):   x^T tile [n=32][k=256] bf16, 16B-chunk XOR swizzle
//   [32K,33K): red_max   [33K,34K): red_sum
//   [34K,50K): per-wave logits-transpose scratch (8 x 2KB)
//   [0,64K):   attn tile [n=32][m=1024] bf16 (after softmax barrier)
__global__ __launch_bounds__(512, 4) void fused_attn_mem(
    const float* __restrict__ x,
    const unsigned short* __restrict__ mT,
    const unsigned short* __restrict__ mR,
    float* __restrict__ out,
    float* __restrict__ logits)
{
    __shared__ __align__(16) char lds[65536];
    float* red_max = (float*)(lds + 32768);
    float* red_sum = (float*)(lds + 33792);

    const int tid = threadIdx.x;
    const int w   = tid >> 6;     // wave 0..7
    const int l   = tid & 63;
    const int l15 = l & 15;
    const int l4  = l >> 4;       // 0..3

    const int bid = blockIdx.x;
    const int b   = bid >> 7;          // 8 batches
    const int n0  = (bid & 127) * NT;  // column strip

    // ---- stage x[b][:][n0:n0+32] -> LDS x^T [n][k], bf16, swizzled ----
    {
        const float* xb = x + (size_t)b * KD * ND + n0;
        const int k  = tid >> 1;        // 0..255
        const int nh = (tid & 1) * 16;  // 0 or 16
        const float4* src = reinterpret_cast<const float4*>(xb + (size_t)k * ND + nh);
        float4 v0 = src[0], v1 = src[1], v2 = src[2], v3 = src[3];
        float vals[16] = {v0.x, v0.y, v0.z, v0.w, v1.x, v1.y, v1.z, v1.w,
                          v2.x, v2.y, v2.z, v2.w, v3.x, v3.y, v3.z, v3.w};
        #pragma unroll
        for (int j = 0; j < 16; ++j) {
            const int n = nh + j;
            const int off = n * 512 + (((k >> 3) ^ (n & 7)) << 4) + (k & 7) * 2;
            *(unsigned short*)(lds + off) = bf16_rne(vals[j]);
        }
    }
    __syncthreads();

    // ---- GEMM1: S[m][n] = sum_k mT[m][k] * xT[n][k]; wave owns m-rows [w*128, w*128+128) ----
    f32x4 acc[8][2];
    #pragma unroll
    for (int rt = 0; rt < 8; ++rt)
        #pragma unroll
        for (int ct = 0; ct < 2; ++ct)
            acc[rt][ct] = (f32x4){0.f, 0.f, 0.f, 0.f};

    #pragma unroll
    for (int ks = 0; ks < 8; ++ks) {
        const int kk = ks * 32 + l4 * 8;
        bf16x8 bfr[2];
        #pragma unroll
        for (int ct = 0; ct < 2; ++ct) {
            const int n = ct * 16 + l15;
            const int off = n * 512 + (((kk >> 3) ^ (n & 7)) << 4);
            bfr[ct] = *(const bf16x8*)(lds + off);
        }
        #pragma unroll
        for (int rt = 0; rt < 8; ++rt) {
            const int row = w * 128 + rt * 16 + l15;
            const bf16x8 afr = *(const bf16x8*)(mT + (size_t)row * KD + kk);
            acc[rt][0] = __builtin_amdgcn_mfma_f32_16x16x32_bf16(afr, bfr[0], acc[rt][0], 0, 0, 0);
            acc[rt][1] = __builtin_amdgcn_mfma_f32_16x16x32_bf16(afr, bfr[1], acc[rt][1], 0, 0, 0);
        }
    }

    // ---- scale 1/16 + per-column running max ----
    float lmax[2] = {-3e38f, -3e38f};
    #pragma unroll
    for (int rt = 0; rt < 8; ++rt) {
        #pragma unroll
        for (int ct = 0; ct < 2; ++ct) {
            f32x4 v = acc[rt][ct] * 0.0625f;
            acc[rt][ct] = v;
            lmax[ct] = fmaxf(lmax[ct], fmaxf(fmaxf(v[0], v[1]), fmaxf(v[2], v[3])));
        }
    }

    // ---- logits store via per-wave LDS transpose (wave-private scratch, no block barrier) ----
    {
        char* sw = lds + 34816 + w * 2048;   // [16 m][32 n] f32, 16B-chunk XOR swizzle
        float* lg = logits + (size_t)b * MD * ND + n0;
        #pragma unroll
        for (int rt = 0; rt < 8; ++rt) {
            #pragma unroll
            for (int ct = 0; ct < 2; ++ct) {
                const int n = ct * 16 + l15;
                #pragma unroll
                for (int r = 0; r < 4; ++r) {
                    const int mloc = l4 * 4 + r;
                    const int off = mloc * 128 + (((n >> 2) ^ (mloc & 7)) << 4) + ((n & 3) << 2);
                    *(float*)(sw + off) = acc[rt][ct][r];
                }
            }
            __asm__ volatile("s_waitcnt lgkmcnt(0)" ::: "memory");
            __builtin_amdgcn_sched_barrier(0);
            #pragma unroll
            for (int half = 0; half < 2; ++half) {
                const int mloc = (l >> 3) + half * 8;
                const int q = l & 7;
                const f32x4 v = *(const f32x4*)(sw + mloc * 128 + ((q ^ (mloc & 7)) << 4));
                *(f32x4*)(lg + (size_t)(w * 128 + rt * 16 + mloc) * ND + q * 4) = v;
            }
            __asm__ volatile("s_waitcnt lgkmcnt(0)" ::: "memory");
            __builtin_amdgcn_sched_barrier(0);
        }
    }

    // ---- cross-wave column max ----
    #pragma unroll
    for (int ct = 0; ct < 2; ++ct) {
        float m = lmax[ct];
        m = fmaxf(m, __shfl_xor(m, 16, 64));
        m = fmaxf(m, __shfl_xor(m, 32, 64));
        lmax[ct] = m;
    }
    if (l < 16) {
        red_max[(w * 2 + 0) * 16 + l] = lmax[0];
        red_max[(w * 2 + 1) * 16 + l] = lmax[1];
    }
    __syncthreads();

    float cmax[2];
    #pragma unroll
    for (int ct = 0; ct < 2; ++ct) {
        float m = -3e38f;
        #pragma unroll
        for (int ww = 0; ww < 8; ++ww)
            m = fmaxf(m, red_max[(ww * 2 + ct) * 16 + l15]);
        cmax[ct] = m;
    }

    // ---- p = exp(logit - colmax), per-column sum ----
    float lsum[2] = {0.f, 0.f};
    #pragma unroll
    for (int rt = 0; rt < 8; ++rt) {
        #pragma unroll
        for (int ct = 0; ct < 2; ++ct) {
            f32x4 v = acc[rt][ct];
            v[0] = __expf(v[0] - cmax[ct]);
            v[1] = __expf(v[1] - cmax[ct]);
            v[2] = __expf(v[2] - cmax[ct]);
            v[3] = __expf(v[3] - cmax[ct]);
            lsum[ct] += (v[0] + v[1]) + (v[2] + v[3]);
            acc[rt][ct] = v;
        }
    }
    #pragma unroll
    for (int ct = 0; ct < 2; ++ct) {
        float s = lsum[ct];
        s += __shfl_xor(s, 16, 64);
        s += __shfl_xor(s, 32, 64);
        lsum[ct] = s;
    }
    if (l < 16) {
        red_sum[(w * 2 + 0) * 16 + l] = lsum[0];
        red_sum[(w * 2 + 1) * 16 + l] = lsum[1];
    }
    __syncthreads();

    float rs[2];
    #pragma unroll
    for (int ct = 0; ct < 2; ++ct) {
        float s = 0.f;
        #pragma unroll
        for (int ww = 0; ww < 8; ++ww)
            s += red_sum[(ww * 2 + ct) * 16 + l15];
        rs[ct] = 1.0f / s;
    }
    __syncthreads();   // all red/scratch reads done; attn tile may overwrite LDS

    // ---- attn (bf16) into LDS [n][m], 16B-chunk XOR swizzle ----
    #pragma unroll
    for (int rt = 0; rt < 8; ++rt) {
        #pragma unroll
        for (int ct = 0; ct < 2; ++ct) {
            f32x4 v = acc[rt][ct];
            unsigned short h0 = bf16_rne(v[0] * rs[ct]);
            unsigned short h1 = bf16_rne(v[1] * rs[ct]);
            unsigned short h2 = bf16_rne(v[2] * rs[ct]);
            unsigned short h3 = bf16_rne(v[3] * rs[ct]);
            const int m0 = w * 128 + rt * 16 + l4 * 4;
            const int n  = ct * 16 + l15;
            const int off = n * 2048 + (((m0 >> 3) ^ (n & 7)) << 4) + (m0 & 7) * 2;
            *(uint2*)(lds + off) = make_uint2((uint32_t)h0 | ((uint32_t)h1 << 16),
                                              (uint32_t)h2 | ((uint32_t)h3 << 16));
        }
    }
    __syncthreads();

    // ---- GEMM2: out[r][n] = sum_m mR[r][m] * attn[m][n]; wave owns rows [w*32, w*32+32) ----
    f32x4 acc2[2][2];
    #pragma unroll
    for (int rtile = 0; rtile < 2; ++rtile)
        #pragma unroll
        for (int ct = 0; ct < 2; ++ct)
            acc2[rtile][ct] = (f32x4){0.f, 0.f, 0.f, 0.f};

    #pragma unroll 4
    for (int ks = 0; ks < 32; ++ks) {
        const int mk = ks * 32 + l4 * 8;
        bf16x8 b2[2];
        #pragma unroll
        for (int ct = 0; ct < 2; ++ct) {
            const int n = ct * 16 + l15;
            const int off = n * 2048 + (((mk >> 3) ^ (n & 7)) << 4);
            b2[ct] = *(const bf16x8*)(lds + off);
        }
        #pragma unroll
        for (int rtile = 0; rtile < 2; ++rtile) {
            const bf16x8 a2 = *(const bf16x8*)(mR + (size_t)(w * 32 + rtile * 16 + l15) * MD + mk);
            acc2[rtile][0] = __builtin_amdgcn_mfma_f32_16x16x32_bf16(a2, b2[0], acc2[rtile][0], 0, 0, 0);
            acc2[rtile][1] = __builtin_amdgcn_mfma_f32_16x16x32_bf16(a2, b2[1], acc2[rtile][1], 0, 0, 0);
        }
    }

    float* ob = out + (size_t)b * KD * ND + n0;
    #pragma unroll
    for (int rtile = 0; rtile < 2; ++rtile) {
        #pragma unroll
        for (int ct = 0; ct < 2; ++ct) {
            const int n  = ct * 16 + l15;
            const int r0 = w * 32 + rtile * 16 + l4 * 4;
            ob[(size_t)(r0 + 0) * ND + n] = acc2[rtile][ct][0];
            ob[(size_t)(r0 + 1) * ND + n] = acc2[rtile][ct][1];
            ob[(size_t)(r0 + 2) * ND + n] = acc2[rtile][ct][2];
            ob[(size_t)(r0 + 3) * ND + n] = acc2[rtile][ct][3];
        }
    }
}

extern "C" void kernel_launch(void* const* d_in, const int* in_sizes, int n_in,
                              void* d_out, int out_size, void* d_ws, size_t ws_size,
                              hipStream_t stream) {
    (void)in_sizes; (void)n_in; (void)out_size; (void)ws_size;
    const float* x   = (const float*)d_in[0];
    // d_in[1] (mask) is a forward no-op
    const float* mem = (const float*)d_in[2];

    float* out    = (float*)d_out;
    float* logits = (float*)d_out + (size_t)BQ * KD * ND;

    unsigned short* mT = (unsigned short*)d_ws;        // [1024][256] bf16
    unsigned short* mR = mT + (size_t)MD * KD;         // [256][1024] bf16

    prep_mem<<<dim3(256), dim3(256), 0, stream>>>(mem, mT, mR);
    fused_attn_mem<<<dim3(BQ * (ND / NT)), dim3(512), 0, stream>>>(x, mT, mR, out, logits);
}

// Round 3
// 112.056 us; speedup vs baseline: 1.3338x; 1.2378x over previous
//
#include <hip/hip_runtime.h>
#include <stdint.h>

// logits = (mem^T @ x)/16 ; attn = softmax_M(logits) ; out = mem @ attn
// B=8, K=256, M=1024, N=4096. Fully fused; logits written once as 256B row chunks.

typedef __attribute__((ext_vector_type(8))) __bf16 bf16x8;
typedef __attribute__((ext_vector_type(4))) float f32x4;

#define BQ 8
#define KD 256
#define MD 1024
#define ND 4096
#define NT 64

__device__ __forceinline__ unsigned short bf16_rne(float f) {
    union { float f; uint32_t u; } c; c.f = f;
    uint32_t u = c.u;
    uint32_t r = (u + 0x7FFFu + ((u >> 16) & 1u)) >> 16;
    return (unsigned short)r;
}

// mem (f32 256x1024) -> mT bf16 [1024][256] (GEMM1 A-frags), mR bf16 [256][1024] (GEMM2 A-frags)
__global__ void prep_mem(const float* __restrict__ mem,
                         unsigned short* __restrict__ mT,
                         unsigned short* __restrict__ mR) {
    const int k = blockIdx.x;   // 0..255
    const int t = threadIdx.x;  // 0..255
    float4 v = reinterpret_cast<const float4*>(mem + (size_t)k * MD)[t];
    unsigned short h0 = bf16_rne(v.x), h1 = bf16_rne(v.y),
                   h2 = bf16_rne(v.z), h3 = bf16_rne(v.w);
    reinterpret_cast<uint2*>(mR + (size_t)k * MD)[t] =
        make_uint2((uint32_t)h0 | ((uint32_t)h1 << 16),
                   (uint32_t)h2 | ((uint32_t)h3 << 16));
    const int mm = t * 4;
    mT[(size_t)(mm + 0) * KD + k] = h0;
    mT[(size_t)(mm + 1) * KD + k] = h1;
    mT[(size_t)(mm + 2) * KD + k] = h2;
    mT[(size_t)(mm + 3) * KD + k] = h3;
}

// One workgroup = (batch b, 64-column strip). 16 waves, 1024 threads, 1 block/CU.
// Dynamic LDS 160 KiB:
//   [0,32K):    x^T tile [n=64][k=256] bf16, 16B-chunk XOR swizzle
//     (aliased after GEMM1: [0,4K) red_max, [4K,8K) red_sum)
//   [32K,160K): attn tile [n=64][m=1024] bf16 (phase 3+)
//     (aliased before attn fill: per-wave transpose scratch, 16 x 4608B)
__global__ __launch_bounds__(1024, 4) void fused_attn_mem(
    const float* __restrict__ x,
    const unsigned short* __restrict__ mT,
    const unsigned short* __restrict__ mR,
    float* __restrict__ out,
    float* __restrict__ logits)
{
    extern __shared__ char lds[];
    float* red_max = (float*)(lds);
    float* red_sum = (float*)(lds + 4096);

    const int tid = threadIdx.x;
    const int w   = tid >> 6;     // wave 0..15
    const int l   = tid & 63;
    const int l15 = l & 15;
    const int l4  = l >> 4;       // 0..3

    // strip mapping: 8 adjacent strips (2KB of each row) per XCD group
    const int bid = blockIdx.x;         // 512 blocks
    const int g   = bid & 7;            // XCD (dispatch round-robin)
    const int j   = bid >> 3;           // 0..63
    const int strip = g * 8 + (j & 7);  // 0..63
    const int b     = j >> 3;           // 0..7
    const int n0    = strip * NT;

    // ---- stage x[b][:][n0:n0+64] -> LDS x^T [n][k], bf16, swizzled ----
    {
        const float* xb = x + (size_t)b * KD * ND + n0;
        const int k  = tid >> 2;        // 0..255
        const int nh = (tid & 3) * 16;  // 0,16,32,48
        const float4* src = reinterpret_cast<const float4*>(xb + (size_t)k * ND + nh);
        float4 v0 = src[0], v1 = src[1], v2 = src[2], v3 = src[3];
        float vals[16] = {v0.x, v0.y, v0.z, v0.w, v1.x, v1.y, v1.z, v1.w,
                          v2.x, v2.y, v2.z, v2.w, v3.x, v3.y, v3.z, v3.w};
        #pragma unroll
        for (int jj = 0; jj < 16; ++jj) {
            const int n = nh + jj;
            const int off = n * 512 + (((k >> 3) ^ (n & 7)) << 4) + (k & 7) * 2;
            *(unsigned short*)(lds + off) = bf16_rne(vals[jj]);
        }
    }
    __syncthreads();   // S1

    // ---- GEMM1: S[m][n]; wave owns m-rows [w*64, w*64+64) x all 64 n ----
    f32x4 acc[4][4];
    #pragma unroll
    for (int rt = 0; rt < 4; ++rt)
        #pragma unroll
        for (int ct = 0; ct < 4; ++ct)
            acc[rt][ct] = (f32x4){0.f, 0.f, 0.f, 0.f};

    #pragma unroll
    for (int ks = 0; ks < 8; ++ks) {
        const int kk = ks * 32 + l4 * 8;
        bf16x8 bfr[4];
        #pragma unroll
        for (int ct = 0; ct < 4; ++ct) {
            const int n = ct * 16 + l15;
            const int off = n * 512 + (((kk >> 3) ^ (n & 7)) << 4);
            bfr[ct] = *(const bf16x8*)(lds + off);
        }
        #pragma unroll
        for (int rt = 0; rt < 4; ++rt) {
            const int row = w * 64 + rt * 16 + l15;
            const bf16x8 afr = *(const bf16x8*)(mT + (size_t)row * KD + kk);
            #pragma unroll
            for (int ct = 0; ct < 4; ++ct)
                acc[rt][ct] = __builtin_amdgcn_mfma_f32_16x16x32_bf16(afr, bfr[ct], acc[rt][ct], 0, 0, 0);
        }
    }

    // ---- scale 1/16 + per-column running max ----
    float lmax[4] = {-3e38f, -3e38f, -3e38f, -3e38f};
    #pragma unroll
    for (int rt = 0; rt < 4; ++rt) {
        #pragma unroll
        for (int ct = 0; ct < 4; ++ct) {
            f32x4 v = acc[rt][ct] * 0.0625f;
            acc[rt][ct] = v;
            lmax[ct] = fmaxf(lmax[ct], fmaxf(fmaxf(v[0], v[1]), fmaxf(v[2], v[3])));
        }
    }

    // ---- logits store via per-wave LDS transpose -> 256B contiguous dwordx4 rows ----
    {
        char* sw = lds + 32768 + w * 4608;   // [16 m][68 dword] f32 (pad 68 for banks)
        float* lg = logits + (size_t)b * MD * ND + n0;
        #pragma unroll
        for (int rt = 0; rt < 4; ++rt) {
            #pragma unroll
            for (int ct = 0; ct < 4; ++ct) {
                const int n = ct * 16 + l15;
                #pragma unroll
                for (int r = 0; r < 4; ++r) {
                    const int mloc = l4 * 4 + r;
                    *(float*)(sw + mloc * 272 + n * 4) = acc[rt][ct][r];
                }
            }
            __asm__ volatile("s_waitcnt lgkmcnt(0)" ::: "memory");
            __builtin_amdgcn_sched_barrier(0);
            #pragma unroll
            for (int p = 0; p < 4; ++p) {
                const int mloc = p * 4 + l4;
                const f32x4 v = *(const f32x4*)(sw + mloc * 272 + l15 * 16);
                *(f32x4*)(lg + (size_t)(w * 64 + rt * 16 + mloc) * ND + l15 * 4) = v;
            }
            __asm__ volatile("s_waitcnt lgkmcnt(0)" ::: "memory");
            __builtin_amdgcn_sched_barrier(0);
        }
    }

    // ---- cross-wave column max ----
    #pragma unroll
    for (int ct = 0; ct < 4; ++ct) {
        float m = lmax[ct];
        m = fmaxf(m, __shfl_xor(m, 16, 64));
        m = fmaxf(m, __shfl_xor(m, 32, 64));
        lmax[ct] = m;
    }
    __syncthreads();   // S2: all x-tile reads + scratch reads done; red region safe
    if (l < 16) {
        #pragma unroll
        for (int ct = 0; ct < 4; ++ct)
            red_max[(w * 4 + ct) * 16 + l] = lmax[ct];
    }
    __syncthreads();   // S3

    float cmax[4];
    #pragma unroll
    for (int ct = 0; ct < 4; ++ct) {
        float m = -3e38f;
        #pragma unroll
        for (int ww = 0; ww < 16; ++ww)
            m = fmaxf(m, red_max[(ww * 4 + ct) * 16 + l15]);
        cmax[ct] = m;
    }

    // ---- p = exp(logit - colmax), per-column sum ----
    float lsum[4] = {0.f, 0.f, 0.f, 0.f};
    #pragma unroll
    for (int rt = 0; rt < 4; ++rt) {
        #pragma unroll
        for (int ct = 0; ct < 4; ++ct) {
            f32x4 v = acc[rt][ct];
            v[0] = __expf(v[0] - cmax[ct]);
            v[1] = __expf(v[1] - cmax[ct]);
            v[2] = __expf(v[2] - cmax[ct]);
            v[3] = __expf(v[3] - cmax[ct]);
            lsum[ct] += (v[0] + v[1]) + (v[2] + v[3]);
            acc[rt][ct] = v;
        }
    }
    #pragma unroll
    for (int ct = 0; ct < 4; ++ct) {
        float s = lsum[ct];
        s += __shfl_xor(s, 16, 64);
        s += __shfl_xor(s, 32, 64);
        lsum[ct] = s;
    }
    if (l < 16) {
        #pragma unroll
        for (int ct = 0; ct < 4; ++ct)
            red_sum[(w * 4 + ct) * 16 + l] = lsum[ct];
    }
    __syncthreads();   // S4

    float rs[4];
    #pragma unroll
    for (int ct = 0; ct < 4; ++ct) {
        float s = 0.f;
        #pragma unroll
        for (int ww = 0; ww < 16; ++ww)
            s += red_sum[(ww * 4 + ct) * 16 + l15];
        rs[ct] = 1.0f / s;
    }

    // ---- attn (bf16) into LDS [n=64][m=1024], 16B-chunk XOR swizzle ----
    #pragma unroll
    for (int rt = 0; rt < 4; ++rt) {
        #pragma unroll
        for (int ct = 0; ct < 4; ++ct) {
            f32x4 v = acc[rt][ct];
            unsigned short h0 = bf16_rne(v[0] * rs[ct]);
            unsigned short h1 = bf16_rne(v[1] * rs[ct]);
            unsigned short h2 = bf16_rne(v[2] * rs[ct]);
            unsigned short h3 = bf16_rne(v[3] * rs[ct]);
            const int m0 = w * 64 + rt * 16 + l4 * 4;
            const int n  = ct * 16 + l15;
            const int off = 32768 + n * 2048 + (((m0 >> 3) ^ (n & 7)) << 4) + (m0 & 7) * 2;
            *(uint2*)(lds + off) = make_uint2((uint32_t)h0 | ((uint32_t)h1 << 16),
                                              (uint32_t)h2 | ((uint32_t)h3 << 16));
        }
    }
    __syncthreads();   // S5

    // ---- GEMM2: out[r][n] = sum_m mR[r][m]*attn[m][n]; wave owns 16 rows ----
    f32x4 acc2[4];
    #pragma unroll
    for (int ct = 0; ct < 4; ++ct)
        acc2[ct] = (f32x4){0.f, 0.f, 0.f, 0.f};

    const unsigned short* arow = mR + (size_t)(w * 16 + l15) * MD;
    #pragma unroll 4
    for (int ks = 0; ks < 32; ++ks) {
        const int mk = ks * 32 + l4 * 8;
        const bf16x8 a2 = *(const bf16x8*)(arow + mk);
        #pragma unroll
        for (int ct = 0; ct < 4; ++ct) {
            const int n = ct * 16 + l15;
            const int off = 32768 + n * 2048 + (((mk >> 3) ^ (n & 7)) << 4);
            const bf16x8 b2 = *(const bf16x8*)(lds + off);
            acc2[ct] = __builtin_amdgcn_mfma_f32_16x16x32_bf16(a2, b2, acc2[ct], 0, 0, 0);
        }
    }
    __syncthreads();   // S6: attn reads done; scratch region reusable

    // ---- out store via per-wave LDS transpose -> 256B contiguous dwordx4 rows ----
    {
        char* sw = lds + 32768 + w * 4608;
        float* ob = out + (size_t)b * KD * ND + n0;
        #pragma unroll
        for (int ct = 0; ct < 4; ++ct) {
            const int n = ct * 16 + l15;
            #pragma unroll
            for (int r = 0; r < 4; ++r) {
                const int rr = l4 * 4 + r;
                *(float*)(sw + rr * 272 + n * 4) = acc2[ct][r];
            }
        }
        __asm__ volatile("s_waitcnt lgkmcnt(0)" ::: "memory");
        __builtin_amdgcn_sched_barrier(0);
        #pragma unroll
        for (int p = 0; p < 4; ++p) {
            const int rr = p * 4 + l4;
            const f32x4 v = *(const f32x4*)(sw + rr * 272 + l15 * 16);
            *(f32x4*)(ob + (size_t)(w * 16 + rr) * ND + l15 * 4) = v;
        }
    }
}

extern "C" void kernel_launch(void* const* d_in, const int* in_sizes, int n_in,
                              void* d_out, int out_size, void* d_ws, size_t ws_size,
                              hipStream_t stream) {
    (void)in_sizes; (void)n_in; (void)out_size; (void)ws_size;
    const float* x   = (const float*)d_in[0];
    // d_in[1] (mask) is a forward no-op
    const float* mem = (const float*)d_in[2];

    float* out    = (float*)d_out;
    float* logits = (float*)d_out + (size_t)BQ * KD * ND;

    unsigned short* mT = (unsigned short*)d_ws;        // [1024][256] bf16
    unsigned short* mR = mT + (size_t)MD * KD;         // [256][1024] bf16

    static int lds_attr_set = 0;   // idempotent host-side attribute, capture-safe
    if (!lds_attr_set) {
        hipFuncSetAttribute(reinterpret_cast<const void*>(&fused_attn_mem),
                            hipFuncAttributeMaxDynamicSharedMemorySize, 163840);
        lds_attr_set = 1;
    }

    prep_mem<<<dim3(256), dim3(256), 0, stream>>>(mem, mT, mR);
    fused_attn_mem<<<dim3(BQ * (ND / NT)), dim3(1024), 163840, stream>>>(x, mT, mR, out, logits);
}